// Round 2
// baseline (559.230 us; speedup 1.0000x reference)
//
#include <hip/hip_runtime.h>

// Problem constants (from reference)
constexpr int Kk   = 21;
constexpr int Hh   = 512, Ww = 512;
constexpr int HO   = 492, WO = 492;          // valid conv output dims
constexpr int Cc   = 10;                     // center offset
constexpr int CTRi = 220;                    // center channel idx (dropped)
constexpr int NCH  = 440;                    // K*K - 1
constexpr int ROW4 = WO / 4;                 // 123 float4 per row (exact, 16B aligned rows)
constexpr int N4S  = NCH * HO * ROW4;        // 26,627,040 float4s of w_ij
constexpr int N4F  = Hh * Ww / 4;            // 65,536 float4s for fidelity

typedef float floatx4 __attribute__((ext_vector_type(4)));   // native vec: nontemporal-ok

#define TPB  256
#define NB_S 1024
#define NB_F 64

__device__ __forceinline__ float block_reduce_256(float v) {
    #pragma unroll
    for (int off = 32; off; off >>= 1) v += __shfl_down(v, off, 64);
    __shared__ float smem[TPB / 64];
    const int lane = threadIdx.x & 63;
    const int wid  = threadIdx.x >> 6;
    if (lane == 0) smem[wid] = v;
    __syncthreads();
    float r = 0.f;
    if (threadIdx.x == 0) {
        #pragma unroll
        for (int k = 0; k < TPB / 64; ++k) r += smem[k];
    }
    return r;
}

// Streams w_ij once (float4, nontemporal); output rows come from L1/L2.
__global__ __launch_bounds__(TPB) void smooth_partial_kernel(
        const float* __restrict__ outp,
        const float* __restrict__ w,
        const float* __restrict__ bias,
        float* __restrict__ partial)
{
    float acc = 0.f;
    const int stride = gridDim.x * blockDim.x;
    for (int q = blockIdx.x * blockDim.x + threadIdx.x; q < N4S; q += stride) {
        // q -> (n, i, j): all divisors are compile-time constants (magic-mul)
        const int r  = q / ROW4;            // row index = n*HO + i
        const int j  = (q - r * ROW4) * 4;  // column start
        const int n  = r / HO;
        const int i  = r - n * HO;
        const int kk = n + (n >= CTRi ? 1 : 0);   // skip dropped center channel
        const int ki = kk / Kk;
        const int kj = kk - ki * Kk;

        const floatx4 w4 = __builtin_nontemporal_load(((const floatx4*)w) + q);

        const float* crow = outp + (i + Cc) * Ww + (Cc + j);   // center taps
        const float* nrow = outp + (i + ki) * Ww + (kj + j);   // neighbor taps
        const float  b    = bias[n];

        const float d0 = crow[0] - nrow[0] + b;
        const float d1 = crow[1] - nrow[1] + b;
        const float d2 = crow[2] - nrow[2] + b;
        const float d3 = crow[3] - nrow[3] + b;

        acc += w4.x * d0 * d0 + w4.y * d1 * d1 + w4.z * d2 * d2 + w4.w * d3 * d3;
    }
    const float bsum = block_reduce_256(acc);
    if (threadIdx.x == 0) partial[blockIdx.x] = bsum;
}

__global__ __launch_bounds__(TPB) void fid_partial_kernel(
        const float* __restrict__ outp,
        const float* __restrict__ targ,
        float* __restrict__ partial)
{
    float acc = 0.f;
    const int stride = gridDim.x * blockDim.x;
    for (int q = blockIdx.x * blockDim.x + threadIdx.x; q < N4F; q += stride) {
        const floatx4 a = ((const floatx4*)outp)[q];
        const floatx4 t = ((const floatx4*)targ)[q];
        const float d0 = a.x - t.x, d1 = a.y - t.y, d2 = a.z - t.z, d3 = a.w - t.w;
        acc += d0 * d0 + d1 * d1 + d2 * d2 + d3 * d3;
    }
    const float bsum = block_reduce_256(acc);
    if (threadIdx.x == 0) partial[blockIdx.x] = bsum;
}

// Single wave: shuffle-only reduction of the partial arrays + final scaling.
__global__ __launch_bounds__(64) void finalize_kernel(
        const float* __restrict__ ps,
        const float* __restrict__ pf,
        float* __restrict__ out)
{
    const int t = threadIdx.x;
    float s = 0.f;
    for (int i = t; i < NB_S; i += 64) s += ps[i];
    float f = pf[t];   // NB_F == 64
    #pragma unroll
    for (int off = 32; off; off >>= 1) {
        s += __shfl_down(s, off, 64);
        f += __shfl_down(f, off, 64);
    }
    if (t == 0) {
        // smooth = H*W*LAM * mean(w*d*d) = S * (512*512*128)/(440*492*492)
        const float SCALE_S = (float)((512.0 * 512.0 * 128.0) / (440.0 * 492.0 * 492.0));
        const float SCALE_F = 1.0f / (512.0f * 512.0f);
        out[0] = s * SCALE_S + f * SCALE_F;
    }
}

extern "C" void kernel_launch(void* const* d_in, const int* in_sizes, int n_in,
                              void* d_out, int out_size, void* d_ws, size_t ws_size,
                              hipStream_t stream) {
    const float* outp = (const float*)d_in[0];   // output (512,512)
    const float* targ = (const float*)d_in[1];   // target (512,512)
    const float* w    = (const float*)d_in[2];   // w_ij (440,492,492)
    const float* bias = (const float*)d_in[3];   // bias (440,)

    float* ps = (float*)d_ws;        // NB_S partials
    float* pf = ps + NB_S;           // NB_F partials

    smooth_partial_kernel<<<NB_S, TPB, 0, stream>>>(outp, w, bias, ps);
    fid_partial_kernel<<<NB_F, TPB, 0, stream>>>(outp, targ, pf);
    finalize_kernel<<<1, 64, 0, stream>>>(ps, pf, (float*)d_out);
}

// Round 3
// 524.950 us; speedup vs baseline: 1.0653x; 1.0653x over previous
//
#include <hip/hip_runtime.h>

// Problem constants (from reference)
constexpr int Kk   = 21;
constexpr int Hh   = 512, Ww = 512;
constexpr int HO   = 492, WO = 492;          // valid conv output dims
constexpr int Cc   = 10;                     // center offset
constexpr int CTRi = 220;                    // center channel idx (dropped)
constexpr int NCH  = 440;                    // K*K - 1
constexpr int ROW4 = WO / 4;                 // 123 float4 per w row (exact, 16B aligned)
constexpr int N4F  = Hh * Ww / 4;            // 65,536 float4s for fidelity

constexpr int RSPLIT = HO / 2;               // 246 row-blocks, 2 rows each
constexpr int CSPLIT = 8;                    // channel splits
constexpr int NPB    = NCH / CSPLIT;         // 55 channels per block
constexpr int NBLK   = RSPLIT * CSPLIT;      // 1968 blocks

// smooth = H*W*LAM * mean(w*d*d) = S_raw * SCALE_S ; fid = F_raw * SCALE_F
// fold fid into the same accumulator pre-scaled by SCALE_F/SCALE_S.
constexpr float SCALE_S  = (float)((512.0 * 512.0 * 128.0) / (440.0 * 492.0 * 492.0));
constexpr float FID_RATIO = (float)((1.0 / (512.0 * 512.0)) /
                                    ((512.0 * 512.0 * 128.0) / (440.0 * 492.0 * 492.0)));

typedef float floatx4 __attribute__((ext_vector_type(4)));

#define TPB 256

__device__ __forceinline__ float block_reduce_256(float v) {
    #pragma unroll
    for (int off = 32; off; off >>= 1) v += __shfl_down(v, off, 64);
    __shared__ float smem[TPB / 64];
    const int lane = threadIdx.x & 63;
    const int wid  = threadIdx.x >> 6;
    if (lane == 0) smem[wid] = v;
    __syncthreads();
    float r = 0.f;
    if (threadIdx.x == 0) {
        #pragma unroll
        for (int k = 0; k < TPB / 64; ++k) r += smem[k];
    }
    return r;
}

// One block: 2 output rows x 55 channels. n is block-uniform -> bias scalar,
// center taps register-resident, neighbor taps from L1/L2-resident outp rows.
__global__ __launch_bounds__(TPB) void main_kernel(
        const float* __restrict__ outp,
        const float* __restrict__ targ,
        const float* __restrict__ w,
        const float* __restrict__ bias,
        float* __restrict__ partial)
{
    const int t = threadIdx.x;
    float acc = 0.f;

    // ---- fused fidelity: first N4F global threads take one float4 each ----
    {
        const int fq = blockIdx.x * TPB + t;
        if (fq < N4F) {
            const floatx4 a  = ((const floatx4*)outp)[fq];
            const floatx4 tg = ((const floatx4*)targ)[fq];
            const float d0 = a.x - tg.x, d1 = a.y - tg.y,
                        d2 = a.z - tg.z, d3 = a.w - tg.w;
            acc = (d0 * d0 + d1 * d1 + d2 * d2 + d3 * d3) * FID_RATIO;
        }
    }

    // ---- smooth term ----
    const int rowblk = blockIdx.x % RSPLIT;
    const int csplit = blockIdx.x / RSPLIT;
    const int n0     = csplit * NPB;

    if (t < 2 * ROW4) {                       // 246 active threads
        const int di = (t >= ROW4) ? 1 : 0;
        const int j4 = t - di * ROW4;
        const int i  = rowblk * 2 + di;       // w-plane row
        const int j  = 4 * j4;                // w-plane col (float units)

        // center taps: invariant over all channels
        const float* crow = outp + (i + Cc) * Ww + (Cc + j);
        const float c0 = crow[0], c1 = crow[1], c2 = crow[2], c3 = crow[3];

        const float* obase = outp + i * Ww + j;    // + ki*Ww + kj gives neighbor
        const floatx4* wp  = (const floatx4*)w + ((long)(n0 * HO + i) * ROW4 + j4);

        float a0 = 0.f, a1 = 0.f, a2 = 0.f, a3 = 0.f;
        #pragma unroll 5
        for (int n = n0; n < n0 + NPB; ++n, wp += HO * ROW4) {
            const int kk = n + (n >= CTRi ? 1 : 0);   // skip dropped center chan
            const int ki = kk / Kk;
            const int kj = kk - ki * Kk;

            const floatx4 w4 = __builtin_nontemporal_load(wp);
            const float   b  = bias[n];               // block-uniform -> s_load
            const float*  nr = obase + ki * Ww + kj;  // L1/L2 hit

            const float d0 = c0 - nr[0] + b;
            const float d1 = c1 - nr[1] + b;
            const float d2 = c2 - nr[2] + b;
            const float d3 = c3 - nr[3] + b;

            a0 += w4.x * d0 * d0;
            a1 += w4.y * d1 * d1;
            a2 += w4.z * d2 * d2;
            a3 += w4.w * d3 * d3;
        }
        acc += (a0 + a1) + (a2 + a3);
    }

    const float bsum = block_reduce_256(acc);
    if (t == 0) partial[blockIdx.x] = bsum;
}

__global__ __launch_bounds__(TPB) void finalize_kernel(
        const float* __restrict__ partial,
        float* __restrict__ out)
{
    float v = 0.f;
    for (int idx = threadIdx.x; idx < NBLK; idx += TPB) v += partial[idx];
    const float s = block_reduce_256(v);
    if (threadIdx.x == 0) out[0] = s * SCALE_S;
}

extern "C" void kernel_launch(void* const* d_in, const int* in_sizes, int n_in,
                              void* d_out, int out_size, void* d_ws, size_t ws_size,
                              hipStream_t stream) {
    const float* outp = (const float*)d_in[0];   // output (512,512)
    const float* targ = (const float*)d_in[1];   // target (512,512)
    const float* w    = (const float*)d_in[2];   // w_ij (440,492,492)
    const float* bias = (const float*)d_in[3];   // bias (440,)

    float* partial = (float*)d_ws;               // NBLK partials

    main_kernel<<<NBLK, TPB, 0, stream>>>(outp, targ, w, bias, partial);
    finalize_kernel<<<1, TPB, 0, stream>>>(partial, (float*)d_out);
}

// Round 4
// 523.542 us; speedup vs baseline: 1.0682x; 1.0027x over previous
//
#include <hip/hip_runtime.h>

// Problem constants (from reference)
constexpr int Kk   = 21;
constexpr int Hh   = 512, Ww = 512;
constexpr int HO   = 492, WO = 492;          // valid conv output dims
constexpr int Cc   = 10;                     // center offset
constexpr int CTRi = 220;                    // center channel idx (dropped)
constexpr int NCH  = 440;                    // K*K - 1
constexpr int ROW4 = WO / 4;                 // 123 float4 per w row (exact, 16B aligned)
constexpr int N4F  = Hh * Ww / 4;            // 65,536 float4s for fidelity

constexpr int RSPLIT = HO / 2;               // 246 row-blocks, 2 rows each
constexpr int CSPLIT = 8;                    // channel splits
constexpr int NPB    = NCH / CSPLIT;         // 55 channels per block
constexpr int NBLK   = RSPLIT * CSPLIT;      // 1968 blocks

constexpr float SCALE_S  = (float)((512.0 * 512.0 * 128.0) / (440.0 * 492.0 * 492.0));
constexpr float FID_RATIO = (float)((1.0 / (512.0 * 512.0)) /
                                    ((512.0 * 512.0 * 128.0) / (440.0 * 492.0 * 492.0)));

typedef float floatx4  __attribute__((ext_vector_type(4)));              // 16B aligned
typedef float floatx4u __attribute__((ext_vector_type(4), aligned(4)));  // unaligned-ok

#define TPB 256

__device__ __forceinline__ float block_reduce_256(float v) {
    #pragma unroll
    for (int off = 32; off; off >>= 1) v += __shfl_down(v, off, 64);
    __shared__ float smem[TPB / 64];
    const int lane = threadIdx.x & 63;
    const int wid  = threadIdx.x >> 6;
    if (lane == 0) smem[wid] = v;
    __syncthreads();
    float r = 0.f;
    if (threadIdx.x == 0) {
        #pragma unroll
        for (int k = 0; k < TPB / 64; ++k) r += smem[k];
    }
    return r;
}

// One block: 2 output rows x 55 channels. n block-uniform; center taps in
// registers; neighbor taps via ONE unaligned dwordx4 (L1-resident rows).
__global__ __launch_bounds__(TPB) void main_kernel(
        const float* __restrict__ outp,
        const float* __restrict__ targ,
        const float* __restrict__ w,
        const float* __restrict__ bias,
        float* __restrict__ partial)
{
    const int t = threadIdx.x;
    float acc = 0.f;

    // ---- fused fidelity: first N4F global threads take one float4 each ----
    {
        const int fq = blockIdx.x * TPB + t;
        if (fq < N4F) {
            const floatx4 a  = ((const floatx4*)outp)[fq];
            const floatx4 tg = ((const floatx4*)targ)[fq];
            const float d0 = a.x - tg.x, d1 = a.y - tg.y,
                        d2 = a.z - tg.z, d3 = a.w - tg.w;
            acc = (d0 * d0 + d1 * d1 + d2 * d2 + d3 * d3) * FID_RATIO;
        }
    }

    // ---- smooth term ----
    const int rowblk = blockIdx.x % RSPLIT;
    const int csplit = blockIdx.x / RSPLIT;
    const int n0     = csplit * NPB;

    if (t < 2 * ROW4) {                       // 246 active threads
        const int di = (t >= ROW4) ? 1 : 0;
        const int j4 = t - di * ROW4;
        const int i  = rowblk * 2 + di;       // w-plane row
        const int j  = 4 * j4;                // w-plane col (float units)

        // center taps: invariant over all channels
        const float* crow = outp + (i + Cc) * Ww + (Cc + j);
        const float c0 = crow[0], c1 = crow[1], c2 = crow[2], c3 = crow[3];

        const float* obase = outp + i * Ww + j;    // + ki*Ww + kj gives neighbor
        const floatx4* wp  = (const floatx4*)w + ((long)(n0 * HO + i) * ROW4 + j4);

        float a0 = 0.f, a1 = 0.f, a2 = 0.f, a3 = 0.f;
        #pragma unroll 5
        for (int n = n0; n < n0 + NPB; ++n, wp += HO * ROW4) {
            const int kk = n + (n >= CTRi ? 1 : 0);   // skip dropped center chan
            const int ki = kk / Kk;
            const int kj = kk - ki * Kk;

            const floatx4  w4 = __builtin_nontemporal_load(wp);
            const float    b  = bias[n];                              // uniform
            const floatx4u n4 = *(const floatx4u*)(obase + ki * Ww + kj);

            const float d0 = c0 - n4.x + b;
            const float d1 = c1 - n4.y + b;
            const float d2 = c2 - n4.z + b;
            const float d3 = c3 - n4.w + b;

            a0 += w4.x * d0 * d0;
            a1 += w4.y * d1 * d1;
            a2 += w4.z * d2 * d2;
            a3 += w4.w * d3 * d3;
        }
        acc += (a0 + a1) + (a2 + a3);
    }

    const float bsum = block_reduce_256(acc);
    if (t == 0) partial[blockIdx.x] = bsum;
}

__global__ __launch_bounds__(TPB) void finalize_kernel(
        const float* __restrict__ partial,
        float* __restrict__ out)
{
    float v = 0.f;
    for (int idx = threadIdx.x; idx < NBLK; idx += TPB) v += partial[idx];
    const float s = block_reduce_256(v);
    if (threadIdx.x == 0) out[0] = s * SCALE_S;
}

extern "C" void kernel_launch(void* const* d_in, const int* in_sizes, int n_in,
                              void* d_out, int out_size, void* d_ws, size_t ws_size,
                              hipStream_t stream) {
    const float* outp = (const float*)d_in[0];   // output (512,512)
    const float* targ = (const float*)d_in[1];   // target (512,512)
    const float* w    = (const float*)d_in[2];   // w_ij (440,492,492)
    const float* bias = (const float*)d_in[3];   // bias (440,)

    float* partial = (float*)d_ws;               // NBLK partials

    main_kernel<<<NBLK, TPB, 0, stream>>>(outp, targ, w, bias, partial);
    finalize_kernel<<<1, TPB, 0, stream>>>(partial, (float*)d_out);
}